// Round 15
// baseline (1451.621 us; speedup 1.0000x reference)
//
#include <hip/hip_runtime.h>
#include <hip/hip_bf16.h>
#include <math.h>

typedef __attribute__((ext_vector_type(8))) __bf16 bf16x8;
typedef __attribute__((ext_vector_type(8))) short short8;
typedef __attribute__((ext_vector_type(4))) float f32x4;
typedef __attribute__((ext_vector_type(4))) unsigned short ushort4v;

#define AS1 __attribute__((address_space(1)))
#define AS3 __attribute__((address_space(3)))

__device__ __forceinline__ unsigned short f2bf(float f) {
  __hip_bfloat16 h = __float2bfloat16(f);
  return __builtin_bit_cast(unsigned short, h);
}
__device__ __forceinline__ float bf2f(unsigned short s) {
  unsigned int u = ((unsigned int)s) << 16;
  return __builtin_bit_cast(float, u);
}

// fast exact-shape gelu: 0.5*v*(1+erf(v/sqrt2)), erf via A&S 7.1.26 (|err|<1.5e-7)
__device__ __forceinline__ float fast_gelu(float v) {
  const float x = v * 0.70710678118654752f;
  const float a = __builtin_fabsf(x);
  const float t = __builtin_amdgcn_rcpf(__builtin_fmaf(0.3275911f, a, 1.0f));
  float p = __builtin_fmaf(t, 1.061405429f, -1.453152027f);
  p = __builtin_fmaf(t, p, 1.421413741f);
  p = __builtin_fmaf(t, p, -0.284496736f);
  p = __builtin_fmaf(t, p, 0.254829592f);
  p = p * t;
  const float e = __builtin_amdgcn_exp2f(-a * a * 1.4426950408889634f);
  const float erfa = __builtin_fmaf(-p, e, 1.0f);
  const float erfx = __builtin_copysignf(erfa, x);
  return 0.5f * v * (1.0f + erfx);
}

// ---------- fp32 -> bf16 conversion (nt load + nt store: read-once streams) --
__global__ void cvt_f32_bf16(const f32x4* __restrict__ in,
                             ushort4v* __restrict__ out, size_t n4) {
  size_t i = (size_t)blockIdx.x * blockDim.x + threadIdx.x;
  size_t stride = (size_t)gridDim.x * blockDim.x;
  for (; i < n4; i += stride) {
    f32x4 v = __builtin_nontemporal_load(&in[i]);
    ushort4v o = { f2bf(v.x), f2bf(v.y), f2bf(v.z), f2bf(v.w) };
    __builtin_nontemporal_store(o, &out[i]);
  }
}

#define MFMA16(a, b, c) __builtin_amdgcn_mfma_f32_16x16x32_bf16( \
    __builtin_bit_cast(bf16x8, a), __builtin_bit_cast(bf16x8, b), c, 0, 0, 0)

// ---------- 128x128 bf16 GEMM body (m97 structure): C = A*B^T (+bias) ------
// (r12-verified 822 TF on layer-1) 128x128 tile, BK=64, 4 waves, 32 KB LDS,
// 2 barriers/K-tile, XOR-swizzled LDS (0 conflicts), k-outer MFMA, setprio.
// r14: result stores are NON-TEMPORAL — the 300 MB h_cat / 64 MB eo write
// streams were flushing L3 and turning x/w1cat panel re-reads into HBM
// re-fetch (layer-1 FETCH 1.19 GB vs ~80 MB compulsory).
// EPI 0: Cb[(col>>12)*cZ + row*4096 + (col&4095)] = bf16(gelu(v))  (segmented)
// EPI 1: Cf[row*N+col]  = wgt[row*8+eidx] * v
// EPI 2: Cf[row*N+col] += wgt[row*8+eidx] * v
// EPI 4: Cb[row*N+col]  = bf16(v)            (unweighted partial, bf16)
template<int EPI>
__device__ __forceinline__ void gemm128_body(
    unsigned short* sA, unsigned short* sB,
    const unsigned short* __restrict__ A, int lda,
    const unsigned short* __restrict__ B, int ldb,
    const float* __restrict__ bias,
    unsigned short* __restrict__ Cb, float* __restrict__ Cf, size_t cZ,
    const float* __restrict__ wgt, int eidx,
    int bm, int bn, int N, int K) {
  const int tid  = threadIdx.x;   // 0..255
  const int lane = tid & 63;
  const int wid  = tid >> 6;      // 0..3
  const int wr   = wid >> 1;
  const int wc   = wid & 1;

  const unsigned short* Ab = A + (size_t)bm * lda;
  const unsigned short* Bb = B + (size_t)bn * ldb;

  unsigned aoff[4], boff[4];
  int ldo[4];
#pragma unroll
  for (int i = 0; i < 4; ++i) {
    const int u    = i * 256 + tid;     // 0..1023
    const int lrow = u >> 3;            // 0..127
    const int q    = (u & 7) ^ (lrow & 7);
    aoff[i] = (unsigned)(lrow * lda + q * 8);
    boff[i] = (unsigned)(lrow * ldb + q * 8);
    ldo[i]  = u * 8;
  }

  f32x4 acc[4][4] = {};
  const int rowe  = (lane & 15) * 64;
  const int sw0   = (((lane >> 4)    ) ^ (lane & 7)) * 8;
  const int sw1   = (((lane >> 4) + 4) ^ (lane & 7)) * 8;
  const int abase = wr * 64 * 64;
  const int bbase = wc * 64 * 64;

  const int NT = K >> 6;
  unsigned kofs = 0;
  for (int t = 0; t < NT; ++t) {
    __syncthreads();
#pragma unroll
    for (int i = 0; i < 4; ++i) {
      __builtin_amdgcn_global_load_lds((const AS1 void*)(Ab + aoff[i] + kofs),
          (AS3 void*)(sA + ldo[i]), 16, 0, 0);
      __builtin_amdgcn_global_load_lds((const AS1 void*)(Bb + boff[i] + kofs),
          (AS3 void*)(sB + ldo[i]), 16, 0, 0);
    }
    kofs += 64;
    asm volatile("s_waitcnt vmcnt(0)" ::: "memory");
    __syncthreads();

#pragma unroll
    for (int kk = 0; kk < 2; ++kk) {
      const int sw = kk ? sw1 : sw0;
      short8 af[4], bf[4];
#pragma unroll
      for (int m = 0; m < 4; ++m)
        af[m] = *(const short8*)(sA + abase + m * 1024 + rowe + sw);
#pragma unroll
      for (int n = 0; n < 4; ++n)
        bf[n] = *(const short8*)(sB + bbase + n * 1024 + rowe + sw);
      __builtin_amdgcn_s_setprio(1);
#pragma unroll
      for (int m = 0; m < 4; ++m)
#pragma unroll
        for (int n = 0; n < 4; ++n)
          acc[m][n] = MFMA16(af[m], bf[n], acc[m][n]);
      __builtin_amdgcn_s_setprio(0);
    }
  }

  const int rbase = bm + wr * 64 + ((lane >> 4) << 2);
  const int cbase = bn + wc * 64 + (lane & 15);
  float wv[4][4];
  if (EPI == 1 || EPI == 2) {
#pragma unroll
    for (int m = 0; m < 4; ++m)
#pragma unroll
      for (int r = 0; r < 4; ++r)
        wv[m][r] = wgt[(size_t)(rbase + m * 16 + r) * 8 + eidx];
  }
#pragma unroll
  for (int m = 0; m < 4; ++m) {
#pragma unroll
    for (int n = 0; n < 4; ++n) {
      const int col = cbase + n * 16;
      const float bv = bias[col];
#pragma unroll
      for (int r = 0; r < 4; ++r) {
        const int row = rbase + m * 16 + r;
        const float v = acc[m][n][r] + bv;
        if (EPI == 0) {
          __builtin_nontemporal_store(f2bf(fast_gelu(v)),
              &Cb[(size_t)(col >> 12) * cZ + (size_t)row * 4096 + (col & 4095)]);
        } else if (EPI == 1) {
          Cf[(size_t)row * N + col] = wv[m][r] * v;
        } else if (EPI == 2) {
          Cf[(size_t)row * N + col] += wv[m][r] * v;
        } else {  // EPI == 4
          __builtin_nontemporal_store(f2bf(v), &Cb[(size_t)row * N + col]);
        }
      }
    }
  }
}

// generic wrapper with XCD-aware swizzle (r12 mapping; nwg % 8 == 0)
template<int EPI>
__global__ __launch_bounds__(256, 3)
void gemm128_k(const unsigned short* __restrict__ A, int lda,
               const unsigned short* __restrict__ B,
               const float* __restrict__ bias,
               unsigned short* __restrict__ Cb, float* __restrict__ Cf,
               size_t cZ, const float* __restrict__ wgt, int eidx,
               int N, int K) {
  __shared__ alignas(16) unsigned short sA[8192];
  __shared__ alignas(16) unsigned short sB[8192];
  const int gx  = gridDim.x;
  const int nwg = gx * gridDim.y;
  const int lin = blockIdx.y * gx + blockIdx.x;
  const int cpx = nwg >> 3;
  const int swb = (lin & 7) * cpx + (lin >> 3);
  const int bm = (swb / gx) * 128;
  const int bn = (swb % gx) * 128;
  gemm128_body<EPI>(sA, sB, A, lda, B, K, bias, Cb, Cf, cZ, wgt, eidx,
                    bm, bn, N, K);
}

// merged gate2 + unweighted expert2 (one 3072-block launch, r12 mapping):
//   blocks [0,1024):    gate2  g2 = gelu(h0 @ gW2^T + gb2)      [M,4096]
//   blocks [1024,3072): eo[e] = bf16(h_{1+e} @ eW2[e]^T + eb2[e]) [M,1024]
__global__ __launch_bounds__(256, 3)
void merged_g2e2(const unsigned short* __restrict__ h_cat, size_t SEG,
                 const unsigned short* __restrict__ gW2b,
                 const float* __restrict__ gb2,
                 unsigned short* __restrict__ g2b,
                 const unsigned short* __restrict__ eW2b,
                 const float* __restrict__ eb2,
                 unsigned short* __restrict__ eo_bf, size_t eoZ,
                 int D, int H) {
  __shared__ alignas(16) unsigned short sA[8192];
  __shared__ alignas(16) unsigned short sB[8192];
  const int bid = blockIdx.x;
  if (bid < 1024) {
    const int swb = (bid & 7) * 128 + (bid >> 3);   // bijective on [0,1024)
    const int bx = swb & 31, by = swb >> 5;         // 32 x 32
    gemm128_body<0>(sA, sB, h_cat, H, gW2b, H, gb2, g2b, nullptr,
                    0, nullptr, 0, by * 128, bx * 128, H, H);
  } else {
    const int eb  = bid - 1024;
    const int e   = eb >> 8;                        // 0..7
    const int sub = eb & 255;
    const int swb = (sub & 7) * 32 + (sub >> 3);    // bijective on [0,256)
    const int bx = swb & 7, by = swb >> 3;          // 8 x 32
    gemm128_body<4>(sA, sB, h_cat + (size_t)(1 + e) * SEG, H,
                    eW2b + (size_t)e * D * H, H, eb2 + (size_t)e * D,
                    eo_bf + (size_t)e * eoZ, nullptr, 0, nullptr, 0,
                    by * 128, bx * 128, D, H);
  }
}

// ---------- gate logits (E=8) + softmax, 1 block/token ----------
__global__ void gate_softmax(const unsigned short* __restrict__ g2,
                             const unsigned short* __restrict__ W3,
                             const float* __restrict__ b3,
                             float* __restrict__ wout, int H) {
  const int m = blockIdx.x;
  const int lane = threadIdx.x & 63;
  const int wid  = threadIdx.x >> 6;
  float acc[8] = {0.f, 0.f, 0.f, 0.f, 0.f, 0.f, 0.f, 0.f};
  const unsigned short* grow = g2 + (size_t)m * H;
  for (int k = threadIdx.x * 8; k < H; k += 256 * 8) {
    short8 gv = *(const short8*)(grow + k);
    float gf[8];
#pragma unroll
    for (int j = 0; j < 8; ++j) gf[j] = bf2f((unsigned short)gv[j]);
#pragma unroll
    for (int e = 0; e < 8; ++e) {
      short8 wvv = *(const short8*)(W3 + (size_t)e * H + k);
#pragma unroll
      for (int j = 0; j < 8; ++j) acc[e] += gf[j] * bf2f((unsigned short)wvv[j]);
    }
  }
#pragma unroll
  for (int e = 0; e < 8; ++e)
#pragma unroll
    for (int off = 32; off > 0; off >>= 1) acc[e] += __shfl_down(acc[e], off);
  __shared__ float red[4][8];
  if (lane == 0) {
#pragma unroll
    for (int e = 0; e < 8; ++e) red[wid][e] = acc[e];
  }
  __syncthreads();
  if (threadIdx.x == 0) {
    float l[8], mx = -1e30f, s = 0.f;
#pragma unroll
    for (int e = 0; e < 8; ++e) {
      l[e] = red[0][e] + red[1][e] + red[2][e] + red[3][e] + b3[e];
      mx = fmaxf(mx, l[e]);
    }
#pragma unroll
    for (int e = 0; e < 8; ++e) { l[e] = expf(l[e] - mx); s += l[e]; }
    const float inv = 1.f / s;
#pragma unroll
    for (int e = 0; e < 8; ++e) wout[(size_t)m * 8 + e] = l[e] * inv;
  }
}

// ---------- weighted sum of 8 bf16 expert partials ----------
// unit i = 8 contiguous outputs; row m = i >> rsh (rsh = log2(D/8))
__global__ void reduce8w(const unsigned short* __restrict__ eo,
                         const float* __restrict__ w,
                         float* __restrict__ out, int n8, int rsh) {
  int i = blockIdx.x * 256 + threadIdx.x;
  const int stride = gridDim.x * 256;
  for (; i < n8; i += stride) {
    const float* wm = w + ((size_t)(i >> rsh) << 3);
    float s[8] = {0.f, 0.f, 0.f, 0.f, 0.f, 0.f, 0.f, 0.f};
#pragma unroll
    for (int e = 0; e < 8; ++e) {
      const short8 v = __builtin_nontemporal_load(
          (const short8*)(eo + (size_t)e * n8 * 8 + (size_t)i * 8));
      const float we = wm[e];
#pragma unroll
      for (int j = 0; j < 8; ++j) s[j] += we * bf2f((unsigned short)v[j]);
    }
    f32x4* o = (f32x4*)(out + (size_t)i * 8);
    f32x4 lo = {s[0], s[1], s[2], s[3]};
    f32x4 hi = {s[4], s[5], s[6], s[7]};
    __builtin_nontemporal_store(lo, &o[0]);
    __builtin_nontemporal_store(hi, &o[1]);
  }
}

extern "C" void kernel_launch(void* const* d_in, const int* in_sizes, int n_in,
                              void* d_out, int out_size, void* d_ws, size_t ws_size,
                              hipStream_t stream) {
  const float* x   = (const float*)d_in[0];
  const float* gW1 = (const float*)d_in[1];
  const float* gb1 = (const float*)d_in[2];
  const float* gW2 = (const float*)d_in[3];
  const float* gb2 = (const float*)d_in[4];
  const float* gW3 = (const float*)d_in[5];
  const float* gb3 = (const float*)d_in[6];
  const float* eW1 = (const float*)d_in[7];
  const float* eb1 = (const float*)d_in[8];
  const float* eW2 = (const float*)d_in[9];
  const float* eb2 = (const float*)d_in[10];

  const int M = 4096, D = 1024, H = 4096, E = 8;
  const int NCAT = (1 + E) * H;       // 36864
  const size_t SEG = (size_t)M * H;   // one h segment [M,4096]

  float* outP = (float*)d_out;              // [M, D]
  float* wP   = outP + (size_t)M * D;       // [M, E]

  char* ws = (char*)d_ws;
  size_t off = 0;
  auto alloc = [&](size_t bytes) -> void* {
    void* p = ws + off;
    off += (bytes + 255) & ~(size_t)255;
    return p;
  };
  unsigned short* xb    = (unsigned short*)alloc((size_t)M * D * 2);
  unsigned short* w1cat = (unsigned short*)alloc((size_t)NCAT * D * 2);
  unsigned short* gW2b  = (unsigned short*)alloc((size_t)H * H * 2);
  unsigned short* gW3b  = (unsigned short*)alloc((size_t)E * H * 2);
  unsigned short* eW2b  = (unsigned short*)alloc((size_t)E * D * H * 2);
  unsigned short* g2b   = (unsigned short*)alloc((size_t)M * H * 2);
  float*          b1cat = (float*)alloc((size_t)NCAT * 4);
  unsigned short* h_cat = (unsigned short*)alloc((size_t)M * NCAT * 2);  // 9 segs
  const size_t base_off = off;
  const size_t eo_b = (size_t)E * M * D * 2;   // bf16 partials, 64 MB
  const int tier1 = (ws_size >= base_off + eo_b) ? 1 : 0;

  auto cvt = [&](const float* src, unsigned short* dst, size_t n) {
    size_t n4 = n >> 2;
    size_t b = (n4 + 255) >> 8;
    if (b > 2048) b = 2048;
    cvt_f32_bf16<<<dim3((unsigned)b), dim3(256), 0, stream>>>(
        (const f32x4*)src, (ushort4v*)dst, n4);
  };
  cvt(x,   xb,    (size_t)M * D);
  cvt(gW1, w1cat, (size_t)H * D);
  cvt(eW1, w1cat + (size_t)H * D, (size_t)E * H * D);
  cvt(gW2, gW2b,  (size_t)H * H);
  cvt(gW3, gW3b,  (size_t)E * H);
  cvt(eW2, eW2b,  (size_t)E * D * H);
  hipMemcpyAsync(b1cat, gb1, (size_t)H * 4, hipMemcpyDeviceToDevice, stream);
  hipMemcpyAsync(b1cat + H, eb1, (size_t)E * H * 4, hipMemcpyDeviceToDevice, stream);

  // fused layer-1: h_cat[seg s] = gelu(x @ [gW1;eW1]^T + b1cat)  [M, 36864]
  gemm128_k<0><<<dim3(NCAT / 128, M / 128), dim3(256), 0, stream>>>(
      xb, D, w1cat, b1cat, h_cat, nullptr, SEG, nullptr, 0, NCAT, D);

  if (tier1) {
    unsigned short* eo_bf = (unsigned short*)alloc(eo_b);
    merged_g2e2<<<dim3(3072), dim3(256), 0, stream>>>(
        h_cat, SEG, gW2b, gb2, g2b, eW2b, eb2, eo_bf, (size_t)M * D, D, H);
    gate_softmax<<<dim3(M), dim3(256), 0, stream>>>(g2b, gW3b, gb3, wP, H);
    reduce8w<<<dim3(2048), dim3(256), 0, stream>>>(
        eo_bf, wP, outP, (int)((size_t)M * D / 8), 7 /* log2(D/8) */);
  } else {
    gemm128_k<0><<<dim3(H / 128, M / 128), dim3(256), 0, stream>>>(
        h_cat, H, gW2b, gb2, g2b, nullptr, SEG, nullptr, 0, H, H);
    gate_softmax<<<dim3(M), dim3(256), 0, stream>>>(g2b, gW3b, gb3, wP, H);
    for (int e = 0; e < E; ++e) {
      if (e == 0)
        gemm128_k<1><<<dim3(D / 128, M / 128), dim3(256), 0, stream>>>(
            h_cat + (size_t)(1 + e) * SEG, H, eW2b + (size_t)e * D * H,
            eb2 + (size_t)e * D, nullptr, outP, 0, wP, e, D, H);
      else
        gemm128_k<2><<<dim3(D / 128, M / 128), dim3(256), 0, stream>>>(
            h_cat + (size_t)(1 + e) * SEG, H, eW2b + (size_t)e * D * H,
            eb2 + (size_t)e * D, nullptr, outP, 0, wP, e, D, H);
    }
  }
}

// Round 16
// 1381.389 us; speedup vs baseline: 1.0508x; 1.0508x over previous
//
#include <hip/hip_runtime.h>
#include <hip/hip_bf16.h>
#include <math.h>

typedef __attribute__((ext_vector_type(8))) __bf16 bf16x8;
typedef __attribute__((ext_vector_type(8))) short short8;
typedef __attribute__((ext_vector_type(4))) float f32x4;
typedef __attribute__((ext_vector_type(4))) unsigned short ushort4v;

#define AS1 __attribute__((address_space(1)))
#define AS3 __attribute__((address_space(3)))

__device__ __forceinline__ unsigned short f2bf(float f) {
  __hip_bfloat16 h = __float2bfloat16(f);
  return __builtin_bit_cast(unsigned short, h);
}
__device__ __forceinline__ float bf2f(unsigned short s) {
  unsigned int u = ((unsigned int)s) << 16;
  return __builtin_bit_cast(float, u);
}

// fast exact-shape gelu: 0.5*v*(1+erf(v/sqrt2)), erf via A&S 7.1.26 (|err|<1.5e-7)
__device__ __forceinline__ float fast_gelu(float v) {
  const float x = v * 0.70710678118654752f;
  const float a = __builtin_fabsf(x);
  const float t = __builtin_amdgcn_rcpf(__builtin_fmaf(0.3275911f, a, 1.0f));
  float p = __builtin_fmaf(t, 1.061405429f, -1.453152027f);
  p = __builtin_fmaf(t, p, 1.421413741f);
  p = __builtin_fmaf(t, p, -0.284496736f);
  p = __builtin_fmaf(t, p, 0.254829592f);
  p = p * t;
  const float e = __builtin_amdgcn_exp2f(-a * a * 1.4426950408889634f);
  const float erfa = __builtin_fmaf(-p, e, 1.0f);
  const float erfx = __builtin_copysignf(erfa, x);
  return 0.5f * v * (1.0f + erfx);
}

// ---------- fp32 -> bf16 conversion ----------
__global__ void cvt_f32_bf16(const float4* __restrict__ in,
                             ushort4v* __restrict__ out, size_t n4) {
  size_t i = (size_t)blockIdx.x * blockDim.x + threadIdx.x;
  size_t stride = (size_t)gridDim.x * blockDim.x;
  for (; i < n4; i += stride) {
    float4 v = in[i];
    ushort4v o = { f2bf(v.x), f2bf(v.y), f2bf(v.z), f2bf(v.w) };
    out[i] = o;
  }
}

#define MFMA16(a, b, c) __builtin_amdgcn_mfma_f32_16x16x32_bf16( \
    __builtin_bit_cast(bf16x8, a), __builtin_bit_cast(bf16x8, b), c, 0, 0, 0)

// ---------- 128x128 bf16 GEMM body (m97 structure): C = A*B^T (+bias) ------
// (r12-verified 822 TF on layer-1, best total 1380 us) 128x128 tile, BK=64,
// 4 waves, 32 KB LDS, 2 barriers/K-tile, XOR-swizzled LDS (0 conflicts),
// k-outer MFMA, setprio. Cached stores (nt stores regressed: 2x write
// amplification, memory-side L3 can't be bypassed).
// EPI 0: Cb[(col>>12)*cZ + row*4096 + (col&4095)] = bf16(gelu(v))  (segmented)
// EPI 1: Cf[row*N+col]  = wgt[row*8+eidx] * v
// EPI 2: Cf[row*N+col] += wgt[row*8+eidx] * v
// EPI 4: Cb[row*N+col]  = bf16(v)            (unweighted partial, bf16)
template<int EPI>
__device__ __forceinline__ void gemm128_body(
    unsigned short* sA, unsigned short* sB,
    const unsigned short* __restrict__ A, int lda,
    const unsigned short* __restrict__ B, int ldb,
    const float* __restrict__ bias,
    unsigned short* __restrict__ Cb, float* __restrict__ Cf, size_t cZ,
    const float* __restrict__ wgt, int eidx,
    int bm, int bn, int N, int K) {
  const int tid  = threadIdx.x;   // 0..255
  const int lane = tid & 63;
  const int wid  = tid >> 6;      // 0..3
  const int wr   = wid >> 1;
  const int wc   = wid & 1;

  const unsigned short* Ab = A + (size_t)bm * lda;
  const unsigned short* Bb = B + (size_t)bn * ldb;

  unsigned aoff[4], boff[4];
  int ldo[4];
#pragma unroll
  for (int i = 0; i < 4; ++i) {
    const int u    = i * 256 + tid;     // 0..1023
    const int lrow = u >> 3;            // 0..127
    const int q    = (u & 7) ^ (lrow & 7);
    aoff[i] = (unsigned)(lrow * lda + q * 8);
    boff[i] = (unsigned)(lrow * ldb + q * 8);
    ldo[i]  = u * 8;
  }

  f32x4 acc[4][4] = {};
  const int rowe  = (lane & 15) * 64;
  const int sw0   = (((lane >> 4)    ) ^ (lane & 7)) * 8;
  const int sw1   = (((lane >> 4) + 4) ^ (lane & 7)) * 8;
  const int abase = wr * 64 * 64;
  const int bbase = wc * 64 * 64;

  const int NT = K >> 6;
  unsigned kofs = 0;
  for (int t = 0; t < NT; ++t) {
    __syncthreads();
#pragma unroll
    for (int i = 0; i < 4; ++i) {
      __builtin_amdgcn_global_load_lds((const AS1 void*)(Ab + aoff[i] + kofs),
          (AS3 void*)(sA + ldo[i]), 16, 0, 0);
      __builtin_amdgcn_global_load_lds((const AS1 void*)(Bb + boff[i] + kofs),
          (AS3 void*)(sB + ldo[i]), 16, 0, 0);
    }
    kofs += 64;
    asm volatile("s_waitcnt vmcnt(0)" ::: "memory");
    __syncthreads();

#pragma unroll
    for (int kk = 0; kk < 2; ++kk) {
      const int sw = kk ? sw1 : sw0;
      short8 af[4], bf[4];
#pragma unroll
      for (int m = 0; m < 4; ++m)
        af[m] = *(const short8*)(sA + abase + m * 1024 + rowe + sw);
#pragma unroll
      for (int n = 0; n < 4; ++n)
        bf[n] = *(const short8*)(sB + bbase + n * 1024 + rowe + sw);
      __builtin_amdgcn_s_setprio(1);
#pragma unroll
      for (int m = 0; m < 4; ++m)
#pragma unroll
        for (int n = 0; n < 4; ++n)
          acc[m][n] = MFMA16(af[m], bf[n], acc[m][n]);
      __builtin_amdgcn_s_setprio(0);
    }
  }

  const int rbase = bm + wr * 64 + ((lane >> 4) << 2);
  const int cbase = bn + wc * 64 + (lane & 15);
  float wv[4][4];
  if (EPI == 1 || EPI == 2) {
#pragma unroll
    for (int m = 0; m < 4; ++m)
#pragma unroll
      for (int r = 0; r < 4; ++r)
        wv[m][r] = wgt[(size_t)(rbase + m * 16 + r) * 8 + eidx];
  }
#pragma unroll
  for (int m = 0; m < 4; ++m) {
#pragma unroll
    for (int n = 0; n < 4; ++n) {
      const int col = cbase + n * 16;
      const float bv = bias[col];
#pragma unroll
      for (int r = 0; r < 4; ++r) {
        const int row = rbase + m * 16 + r;
        const float v = acc[m][n][r] + bv;
        if (EPI == 0) {
          Cb[(size_t)(col >> 12) * cZ + (size_t)row * 4096 + (col & 4095)] =
              f2bf(fast_gelu(v));
        } else if (EPI == 1) {
          Cf[(size_t)row * N + col] = wv[m][r] * v;
        } else if (EPI == 2) {
          Cf[(size_t)row * N + col] += wv[m][r] * v;
        } else {  // EPI == 4
          Cb[(size_t)row * N + col] = f2bf(v);
        }
      }
    }
  }
}

// generic wrapper with XCD-aware swizzle (r12 mapping; nwg % 8 == 0)
template<int EPI>
__global__ __launch_bounds__(256, 3)
void gemm128_k(const unsigned short* __restrict__ A, int lda,
               const unsigned short* __restrict__ B,
               const float* __restrict__ bias,
               unsigned short* __restrict__ Cb, float* __restrict__ Cf,
               size_t cZ, const float* __restrict__ wgt, int eidx,
               int N, int K) {
  __shared__ alignas(16) unsigned short sA[8192];
  __shared__ alignas(16) unsigned short sB[8192];
  const int gx  = gridDim.x;
  const int nwg = gx * gridDim.y;
  const int lin = blockIdx.y * gx + blockIdx.x;
  const int cpx = nwg >> 3;
  const int swb = (lin & 7) * cpx + (lin >> 3);
  const int bm = (swb / gx) * 128;
  const int bn = (swb % gx) * 128;
  gemm128_body<EPI>(sA, sB, A, lda, B, K, bias, Cb, Cf, cZ, wgt, eidx,
                    bm, bn, N, K);
}

// merged gate2 + unweighted expert2 (one 3072-block launch, r12 mapping):
//   blocks [0,1024):    gate2  g2 = gelu(h0 @ gW2^T + gb2)      [M,4096]
//   blocks [1024,3072): eo[e] = bf16(h_{1+e} @ eW2[e]^T + eb2[e]) [M,1024]
__global__ __launch_bounds__(256, 3)
void merged_g2e2(const unsigned short* __restrict__ h_cat, size_t SEG,
                 const unsigned short* __restrict__ gW2b,
                 const float* __restrict__ gb2,
                 unsigned short* __restrict__ g2b,
                 const unsigned short* __restrict__ eW2b,
                 const float* __restrict__ eb2,
                 unsigned short* __restrict__ eo_bf, size_t eoZ,
                 int D, int H) {
  __shared__ alignas(16) unsigned short sA[8192];
  __shared__ alignas(16) unsigned short sB[8192];
  const int bid = blockIdx.x;
  if (bid < 1024) {
    const int swb = (bid & 7) * 128 + (bid >> 3);   // bijective on [0,1024)
    const int bx = swb & 31, by = swb >> 5;         // 32 x 32
    gemm128_body<0>(sA, sB, h_cat, H, gW2b, H, gb2, g2b, nullptr,
                    0, nullptr, 0, by * 128, bx * 128, H, H);
  } else {
    const int eb  = bid - 1024;
    const int e   = eb >> 8;                        // 0..7
    const int sub = eb & 255;
    const int swb = (sub & 7) * 32 + (sub >> 3);    // bijective on [0,256)
    const int bx = swb & 7, by = swb >> 3;          // 8 x 32
    gemm128_body<4>(sA, sB, h_cat + (size_t)(1 + e) * SEG, H,
                    eW2b + (size_t)e * D * H, H, eb2 + (size_t)e * D,
                    eo_bf + (size_t)e * eoZ, nullptr, 0, nullptr, 0,
                    by * 128, bx * 128, D, H);
  }
}

// ---------- gate logits (E=8) + softmax, 1 block/token ----------
__global__ void gate_softmax(const unsigned short* __restrict__ g2,
                             const unsigned short* __restrict__ W3,
                             const float* __restrict__ b3,
                             float* __restrict__ wout, int H) {
  const int m = blockIdx.x;
  const int lane = threadIdx.x & 63;
  const int wid  = threadIdx.x >> 6;
  float acc[8] = {0.f, 0.f, 0.f, 0.f, 0.f, 0.f, 0.f, 0.f};
  const unsigned short* grow = g2 + (size_t)m * H;
  for (int k = threadIdx.x * 8; k < H; k += 256 * 8) {
    short8 gv = *(const short8*)(grow + k);
    float gf[8];
#pragma unroll
    for (int j = 0; j < 8; ++j) gf[j] = bf2f((unsigned short)gv[j]);
#pragma unroll
    for (int e = 0; e < 8; ++e) {
      short8 wvv = *(const short8*)(W3 + (size_t)e * H + k);
#pragma unroll
      for (int j = 0; j < 8; ++j) acc[e] += gf[j] * bf2f((unsigned short)wvv[j]);
    }
  }
#pragma unroll
  for (int e = 0; e < 8; ++e)
#pragma unroll
    for (int off = 32; off > 0; off >>= 1) acc[e] += __shfl_down(acc[e], off);
  __shared__ float red[4][8];
  if (lane == 0) {
#pragma unroll
    for (int e = 0; e < 8; ++e) red[wid][e] = acc[e];
  }
  __syncthreads();
  if (threadIdx.x == 0) {
    float l[8], mx = -1e30f, s = 0.f;
#pragma unroll
    for (int e = 0; e < 8; ++e) {
      l[e] = red[0][e] + red[1][e] + red[2][e] + red[3][e] + b3[e];
      mx = fmaxf(mx, l[e]);
    }
#pragma unroll
    for (int e = 0; e < 8; ++e) { l[e] = expf(l[e] - mx); s += l[e]; }
    const float inv = 1.f / s;
#pragma unroll
    for (int e = 0; e < 8; ++e) wout[(size_t)m * 8 + e] = l[e] * inv;
  }
}

// ---------- weighted sum of 8 bf16 expert partials ----------
// unit i = 8 contiguous outputs; row m = i >> rsh (rsh = log2(D/8))
__global__ void reduce8w(const unsigned short* __restrict__ eo,
                         const float* __restrict__ w,
                         float* __restrict__ out, int n8, int rsh) {
  int i = blockIdx.x * 256 + threadIdx.x;
  const int stride = gridDim.x * 256;
  for (; i < n8; i += stride) {
    const float* wm = w + ((size_t)(i >> rsh) << 3);
    float s[8] = {0.f, 0.f, 0.f, 0.f, 0.f, 0.f, 0.f, 0.f};
#pragma unroll
    for (int e = 0; e < 8; ++e) {
      const short8 v = *(const short8*)(eo + (size_t)e * n8 * 8 + (size_t)i * 8);
      const float we = wm[e];
#pragma unroll
      for (int j = 0; j < 8; ++j) s[j] += we * bf2f((unsigned short)v[j]);
    }
    float4* o = (float4*)(out + (size_t)i * 8);
    o[0] = make_float4(s[0], s[1], s[2], s[3]);
    o[1] = make_float4(s[4], s[5], s[6], s[7]);
  }
}

extern "C" void kernel_launch(void* const* d_in, const int* in_sizes, int n_in,
                              void* d_out, int out_size, void* d_ws, size_t ws_size,
                              hipStream_t stream) {
  const float* x   = (const float*)d_in[0];
  const float* gW1 = (const float*)d_in[1];
  const float* gb1 = (const float*)d_in[2];
  const float* gW2 = (const float*)d_in[3];
  const float* gb2 = (const float*)d_in[4];
  const float* gW3 = (const float*)d_in[5];
  const float* gb3 = (const float*)d_in[6];
  const float* eW1 = (const float*)d_in[7];
  const float* eb1 = (const float*)d_in[8];
  const float* eW2 = (const float*)d_in[9];
  const float* eb2 = (const float*)d_in[10];

  const int M = 4096, D = 1024, H = 4096, E = 8;
  const int NCAT = (1 + E) * H;       // 36864
  const size_t SEG = (size_t)M * H;   // one h segment [M,4096]

  float* outP = (float*)d_out;              // [M, D]
  float* wP   = outP + (size_t)M * D;       // [M, E]

  char* ws = (char*)d_ws;
  size_t off = 0;
  auto alloc = [&](size_t bytes) -> void* {
    void* p = ws + off;
    off += (bytes + 255) & ~(size_t)255;
    return p;
  };
  unsigned short* xb    = (unsigned short*)alloc((size_t)M * D * 2);
  unsigned short* w1cat = (unsigned short*)alloc((size_t)NCAT * D * 2);
  unsigned short* gW2b  = (unsigned short*)alloc((size_t)H * H * 2);
  unsigned short* gW3b  = (unsigned short*)alloc((size_t)E * H * 2);
  unsigned short* eW2b  = (unsigned short*)alloc((size_t)E * D * H * 2);
  unsigned short* g2b   = (unsigned short*)alloc((size_t)M * H * 2);
  float*          b1cat = (float*)alloc((size_t)NCAT * 4);
  unsigned short* h_cat = (unsigned short*)alloc((size_t)M * NCAT * 2);  // 9 segs
  const size_t base_off = off;
  const size_t eo_b = (size_t)E * M * D * 2;   // bf16 partials, 64 MB
  const int tier1 = (ws_size >= base_off + eo_b) ? 1 : 0;

  auto cvt = [&](const float* src, unsigned short* dst, size_t n) {
    size_t n4 = n >> 2;
    size_t b = (n4 + 255) >> 8;
    if (b > 2048) b = 2048;
    cvt_f32_bf16<<<dim3((unsigned)b), dim3(256), 0, stream>>>(
        (const float4*)src, (ushort4v*)dst, n4);
  };
  cvt(x,   xb,    (size_t)M * D);
  cvt(gW1, w1cat, (size_t)H * D);
  cvt(eW1, w1cat + (size_t)H * D, (size_t)E * H * D);
  cvt(gW2, gW2b,  (size_t)H * H);
  cvt(gW3, gW3b,  (size_t)E * H);
  cvt(eW2, eW2b,  (size_t)E * D * H);
  hipMemcpyAsync(b1cat, gb1, (size_t)H * 4, hipMemcpyDeviceToDevice, stream);
  hipMemcpyAsync(b1cat + H, eb1, (size_t)E * H * 4, hipMemcpyDeviceToDevice, stream);

  // fused layer-1: h_cat[seg s] = gelu(x @ [gW1;eW1]^T + b1cat)  [M, 36864]
  gemm128_k<0><<<dim3(NCAT / 128, M / 128), dim3(256), 0, stream>>>(
      xb, D, w1cat, b1cat, h_cat, nullptr, SEG, nullptr, 0, NCAT, D);

  if (tier1) {
    unsigned short* eo_bf = (unsigned short*)alloc(eo_b);
    merged_g2e2<<<dim3(3072), dim3(256), 0, stream>>>(
        h_cat, SEG, gW2b, gb2, g2b, eW2b, eb2, eo_bf, (size_t)M * D, D, H);
    gate_softmax<<<dim3(M), dim3(256), 0, stream>>>(g2b, gW3b, gb3, wP, H);
    reduce8w<<<dim3(2048), dim3(256), 0, stream>>>(
        eo_bf, wP, outP, (int)((size_t)M * D / 8), 7 /* log2(D/8) */);
  } else {
    gemm128_k<0><<<dim3(H / 128, M / 128), dim3(256), 0, stream>>>(
        h_cat, H, gW2b, gb2, g2b, nullptr, SEG, nullptr, 0, H, H);
    gate_softmax<<<dim3(M), dim3(256), 0, stream>>>(g2b, gW3b, gb3, wP, H);
    for (int e = 0; e < E; ++e) {
      if (e == 0)
        gemm128_k<1><<<dim3(D / 128, M / 128), dim3(256), 0, stream>>>(
            h_cat + (size_t)(1 + e) * SEG, H, eW2b + (size_t)e * D * H,
            eb2 + (size_t)e * D, nullptr, outP, 0, wP, e, D, H);
      else
        gemm128_k<2><<<dim3(D / 128, M / 128), dim3(256), 0, stream>>>(
            h_cat + (size_t)(1 + e) * SEG, H, eW2b + (size_t)e * D * H,
            eb2 + (size_t)e * D, nullptr, outP, 0, wP, e, D, H);
    }
  }
}

// Round 17
// 945.642 us; speedup vs baseline: 1.5351x; 1.4608x over previous
//
#include <hip/hip_runtime.h>
#include <hip/hip_bf16.h>
#include <math.h>

typedef __attribute__((ext_vector_type(8))) __bf16 bf16x8;
typedef __attribute__((ext_vector_type(8))) short short8;
typedef __attribute__((ext_vector_type(4))) float f32x4;
typedef __attribute__((ext_vector_type(4))) unsigned short ushort4v;

#define AS1 __attribute__((address_space(1)))
#define AS3 __attribute__((address_space(3)))

__device__ __forceinline__ unsigned short f2bf(float f) {
  __hip_bfloat16 h = __float2bfloat16(f);
  return __builtin_bit_cast(unsigned short, h);
}
__device__ __forceinline__ float bf2f(unsigned short s) {
  unsigned int u = ((unsigned int)s) << 16;
  return __builtin_bit_cast(float, u);
}

// fast exact-shape gelu: 0.5*v*(1+erf(v/sqrt2)), erf via A&S 7.1.26 (|err|<1.5e-7)
__device__ __forceinline__ float fast_gelu(float v) {
  const float x = v * 0.70710678118654752f;
  const float a = __builtin_fabsf(x);
  const float t = __builtin_amdgcn_rcpf(__builtin_fmaf(0.3275911f, a, 1.0f));
  float p = __builtin_fmaf(t, 1.061405429f, -1.453152027f);
  p = __builtin_fmaf(t, p, 1.421413741f);
  p = __builtin_fmaf(t, p, -0.284496736f);
  p = __builtin_fmaf(t, p, 0.254829592f);
  p = p * t;
  const float e = __builtin_amdgcn_exp2f(-a * a * 1.4426950408889634f);
  const float erfa = __builtin_fmaf(-p, e, 1.0f);
  const float erfx = __builtin_copysignf(erfa, x);
  return 0.5f * v * (1.0f + erfx);
}

// ---------- fp32 -> bf16 conversion ----------
__global__ void cvt_f32_bf16(const float4* __restrict__ in,
                             ushort4v* __restrict__ out, size_t n4) {
  size_t i = (size_t)blockIdx.x * blockDim.x + threadIdx.x;
  size_t stride = (size_t)gridDim.x * blockDim.x;
  for (; i < n4; i += stride) {
    float4 v = in[i];
    ushort4v o = { f2bf(v.x), f2bf(v.y), f2bf(v.z), f2bf(v.w) };
    out[i] = o;
  }
}

#define MFMA16(a, b, c) __builtin_amdgcn_mfma_f32_16x16x32_bf16( \
    __builtin_bit_cast(bf16x8, a), __builtin_bit_cast(bf16x8, b), c, 0, 0, 0)

// ---------- 128x128 bf16 GEMM body (m97 structure): C = A*B^T (+bias) ------
// (r12-verified 822 TF on layer-1) 128x128 tile, BK=64, 4 waves, 32 KB LDS,
// 2 barriers/K-tile, XOR-swizzled LDS (0 conflicts), k-outer MFMA, setprio.
// EPI 0: Cb[(col>>12)*cZ + row*4096 + (col&4095)] = bf16(gelu(v))  (segmented)
// EPI 4: Cb[row*N+col]  = bf16(v)            (unweighted partial, bf16)
template<int EPI>
__device__ __forceinline__ void gemm128_body(
    unsigned short* sA, unsigned short* sB,
    const unsigned short* __restrict__ A, int lda,
    const unsigned short* __restrict__ B, int ldb,
    const float* __restrict__ bias,
    unsigned short* __restrict__ Cb, size_t cZ,
    int bm, int bn, int N, int K) {
  const int tid  = threadIdx.x;   // 0..255
  const int lane = tid & 63;
  const int wid  = tid >> 6;      // 0..3
  const int wr   = wid >> 1;
  const int wc   = wid & 1;

  const unsigned short* Ab = A + (size_t)bm * lda;
  const unsigned short* Bb = B + (size_t)bn * ldb;

  unsigned aoff[4], boff[4];
  int ldo[4];
#pragma unroll
  for (int i = 0; i < 4; ++i) {
    const int u    = i * 256 + tid;     // 0..1023
    const int lrow = u >> 3;            // 0..127
    const int q    = (u & 7) ^ (lrow & 7);
    aoff[i] = (unsigned)(lrow * lda + q * 8);
    boff[i] = (unsigned)(lrow * ldb + q * 8);
    ldo[i]  = u * 8;
  }

  f32x4 acc[4][4] = {};
  const int rowe  = (lane & 15) * 64;
  const int sw0   = (((lane >> 4)    ) ^ (lane & 7)) * 8;
  const int sw1   = (((lane >> 4) + 4) ^ (lane & 7)) * 8;
  const int abase = wr * 64 * 64;
  const int bbase = wc * 64 * 64;

  const int NT = K >> 6;
  unsigned kofs = 0;
  for (int t = 0; t < NT; ++t) {
    __syncthreads();
#pragma unroll
    for (int i = 0; i < 4; ++i) {
      __builtin_amdgcn_global_load_lds((const AS1 void*)(Ab + aoff[i] + kofs),
          (AS3 void*)(sA + ldo[i]), 16, 0, 0);
      __builtin_amdgcn_global_load_lds((const AS1 void*)(Bb + boff[i] + kofs),
          (AS3 void*)(sB + ldo[i]), 16, 0, 0);
    }
    kofs += 64;
    asm volatile("s_waitcnt vmcnt(0)" ::: "memory");
    __syncthreads();

#pragma unroll
    for (int kk = 0; kk < 2; ++kk) {
      const int sw = kk ? sw1 : sw0;
      short8 af[4], bf[4];
#pragma unroll
      for (int m = 0; m < 4; ++m)
        af[m] = *(const short8*)(sA + abase + m * 1024 + rowe + sw);
#pragma unroll
      for (int n = 0; n < 4; ++n)
        bf[n] = *(const short8*)(sB + bbase + n * 1024 + rowe + sw);
      __builtin_amdgcn_s_setprio(1);
#pragma unroll
      for (int m = 0; m < 4; ++m)
#pragma unroll
        for (int n = 0; n < 4; ++n)
          acc[m][n] = MFMA16(af[m], bf[n], acc[m][n]);
      __builtin_amdgcn_s_setprio(0);
    }
  }

  const int rbase = bm + wr * 64 + ((lane >> 4) << 2);
  const int cbase = bn + wc * 64 + (lane & 15);
#pragma unroll
  for (int m = 0; m < 4; ++m) {
#pragma unroll
    for (int n = 0; n < 4; ++n) {
      const int col = cbase + n * 16;
      const float bv = bias[col];
#pragma unroll
      for (int r = 0; r < 4; ++r) {
        const int row = rbase + m * 16 + r;
        const float v = acc[m][n][r] + bv;
        if (EPI == 0) {
          Cb[(size_t)(col >> 12) * cZ + (size_t)row * 4096 + (col & 4095)] =
              f2bf(fast_gelu(v));
        } else {  // EPI == 4
          Cb[(size_t)row * N + col] = f2bf(v);
        }
      }
    }
  }
}

// generic wrapper with XCD-aware swizzle (r12 mapping; nwg % 8 == 0)
template<int EPI>
__global__ __launch_bounds__(256, 3)
void gemm128_k(const unsigned short* __restrict__ A, int lda,
               const unsigned short* __restrict__ B,
               const float* __restrict__ bias,
               unsigned short* __restrict__ Cb, size_t cZ,
               int N, int K) {
  __shared__ alignas(16) unsigned short sA[8192];
  __shared__ alignas(16) unsigned short sB[8192];
  const int gx  = gridDim.x;
  const int nwg = gx * gridDim.y;
  const int lin = blockIdx.y * gx + blockIdx.x;
  const int cpx = nwg >> 3;
  const int swb = (lin & 7) * cpx + (lin >> 3);
  const int bm = (swb / gx) * 128;
  const int bn = (swb % gx) * 128;
  gemm128_body<EPI>(sA, sB, A, lda, B, K, bias, Cb, cZ, bm, bn, N, K);
}

// merged gate2 + unweighted expert2 (one 3072-block launch, r12 mapping):
//   blocks [0,1024):    gate2  g2 = gelu(h0 @ gW2^T + gb2)      [M,4096]
//   blocks [1024,3072): eo[e] = bf16(h_{1+e} @ eW2[e]^T + eb2[e]) [M,1024]
__global__ __launch_bounds__(256, 3)
void merged_g2e2(const unsigned short* __restrict__ h_cat, size_t SEG,
                 const unsigned short* __restrict__ gW2b,
                 const float* __restrict__ gb2,
                 unsigned short* __restrict__ g2b,
                 const unsigned short* __restrict__ eW2b,
                 const float* __restrict__ eb2,
                 unsigned short* __restrict__ eo_bf, size_t eoZ,
                 int D, int H) {
  __shared__ alignas(16) unsigned short sA[8192];
  __shared__ alignas(16) unsigned short sB[8192];
  const int bid = blockIdx.x;
  if (bid < 1024) {
    const int swb = (bid & 7) * 128 + (bid >> 3);   // bijective on [0,1024)
    const int bx = swb & 31, by = swb >> 5;         // 32 x 32
    gemm128_body<0>(sA, sB, h_cat, H, gW2b, H, gb2, g2b, 0,
                    by * 128, bx * 128, H, H);
  } else {
    const int eb  = bid - 1024;
    const int e   = eb >> 8;                        // 0..7
    const int sub = eb & 255;
    const int swb = (sub & 7) * 32 + (sub >> 3);    // bijective on [0,256)
    const int bx = swb & 7, by = swb >> 3;          // 8 x 32
    gemm128_body<4>(sA, sB, h_cat + (size_t)(1 + e) * SEG, H,
                    eW2b + (size_t)e * D * H, H, eb2 + (size_t)e * D,
                    eo_bf + (size_t)e * eoZ, 0,
                    by * 128, bx * 128, D, H);
  }
}

// ---------- gate logits (E=8) + softmax, 1 block/token ----------
__global__ void gate_softmax(const unsigned short* __restrict__ g2,
                             const unsigned short* __restrict__ W3,
                             const float* __restrict__ b3,
                             float* __restrict__ wout, int H) {
  const int m = blockIdx.x;
  const int lane = threadIdx.x & 63;
  const int wid  = threadIdx.x >> 6;
  float acc[8] = {0.f, 0.f, 0.f, 0.f, 0.f, 0.f, 0.f, 0.f};
  const unsigned short* grow = g2 + (size_t)m * H;
  for (int k = threadIdx.x * 8; k < H; k += 256 * 8) {
    short8 gv = *(const short8*)(grow + k);
    float gf[8];
#pragma unroll
    for (int j = 0; j < 8; ++j) gf[j] = bf2f((unsigned short)gv[j]);
#pragma unroll
    for (int e = 0; e < 8; ++e) {
      short8 wvv = *(const short8*)(W3 + (size_t)e * H + k);
#pragma unroll
      for (int j = 0; j < 8; ++j) acc[e] += gf[j] * bf2f((unsigned short)wvv[j]);
    }
  }
#pragma unroll
  for (int e = 0; e < 8; ++e)
#pragma unroll
    for (int off = 32; off > 0; off >>= 1) acc[e] += __shfl_down(acc[e], off);
  __shared__ float red[4][8];
  if (lane == 0) {
#pragma unroll
    for (int e = 0; e < 8; ++e) red[wid][e] = acc[e];
  }
  __syncthreads();
  if (threadIdx.x == 0) {
    float l[8], mx = -1e30f, s = 0.f;
#pragma unroll
    for (int e = 0; e < 8; ++e) {
      l[e] = red[0][e] + red[1][e] + red[2][e] + red[3][e] + b3[e];
      mx = fmaxf(mx, l[e]);
    }
#pragma unroll
    for (int e = 0; e < 8; ++e) { l[e] = expf(l[e] - mx); s += l[e]; }
    const float inv = 1.f / s;
#pragma unroll
    for (int e = 0; e < 8; ++e) wout[(size_t)m * 8 + e] = l[e] * inv;
  }
}

// ---------- weighted sum of 8 bf16 expert partials ----------
// unit i = 8 contiguous outputs; row m = i >> rsh (rsh = log2(D/8))
__global__ void reduce8w(const unsigned short* __restrict__ eo,
                         const float* __restrict__ w,
                         float* __restrict__ out, int n8, int rsh) {
  int i = blockIdx.x * 256 + threadIdx.x;
  const int stride = gridDim.x * 256;
  for (; i < n8; i += stride) {
    const float* wm = w + ((size_t)(i >> rsh) << 3);
    float s[8] = {0.f, 0.f, 0.f, 0.f, 0.f, 0.f, 0.f, 0.f};
#pragma unroll
    for (int e = 0; e < 8; ++e) {
      const short8 v = *(const short8*)(eo + (size_t)e * n8 * 8 + (size_t)i * 8);
      const float we = wm[e];
#pragma unroll
      for (int j = 0; j < 8; ++j) s[j] += we * bf2f((unsigned short)v[j]);
    }
    float4* o = (float4*)(out + (size_t)i * 8);
    o[0] = make_float4(s[0], s[1], s[2], s[3]);
    o[1] = make_float4(s[4], s[5], s[6], s[7]);
  }
}

extern "C" void kernel_launch(void* const* d_in, const int* in_sizes, int n_in,
                              void* d_out, int out_size, void* d_ws, size_t ws_size,
                              hipStream_t stream) {
  const float* x   = (const float*)d_in[0];
  const float* gW1 = (const float*)d_in[1];
  const float* gb1 = (const float*)d_in[2];
  const float* gW2 = (const float*)d_in[3];
  const float* gb2 = (const float*)d_in[4];
  const float* gW3 = (const float*)d_in[5];
  const float* gb3 = (const float*)d_in[6];
  const float* eW1 = (const float*)d_in[7];
  const float* eb1 = (const float*)d_in[8];
  const float* eW2 = (const float*)d_in[9];
  const float* eb2 = (const float*)d_in[10];

  const int M = 4096, D = 1024, H = 4096, E = 8;
  const int NCAT = (1 + E) * H;       // 36864
  const size_t SEG = (size_t)M * H;   // one h segment [M,4096]

  float* outP = (float*)d_out;              // [M, D]
  float* wP   = outP + (size_t)M * D;       // [M, E]

  char* ws = (char*)d_ws;
  size_t off = 0;
  auto alloc = [&](size_t bytes) -> void* {
    void* p = ws + off;
    off += (bytes + 255) & ~(size_t)255;
    return p;
  };
  unsigned short* xb    = (unsigned short*)alloc((size_t)M * D * 2);
  unsigned short* w1cat = (unsigned short*)alloc((size_t)NCAT * D * 2);  // 75.5 MB
  unsigned short* gW2b  = (unsigned short*)alloc((size_t)H * H * 2);
  unsigned short* gW3b  = (unsigned short*)alloc((size_t)E * H * 2);
  unsigned short* eW2b  = (unsigned short*)alloc((size_t)E * D * H * 2);
  unsigned short* g2b   = (unsigned short*)alloc((size_t)M * H * 2);
  float*          b1cat = (float*)alloc((size_t)NCAT * 4);
  unsigned short* h_cat = (unsigned short*)alloc((size_t)M * NCAT * 2);  // 9 segs

  // eo_bf (64 MB) ALIASES w1cat (75.5 MB): w1cat is dead after layer-1, and
  // merged (which writes eo_bf) launches after layer-1 completes. This keeps
  // total ws at the base ~520 MB and guarantees the merged path always runs
  // (the old ws_size tier test silently fell back to 8 serialized expert
  // GEMMs ~ +500 us when ws was tight).
  unsigned short* eo_bf = w1cat;

  auto cvt = [&](const float* src, unsigned short* dst, size_t n) {
    size_t n4 = n >> 2;
    size_t b = (n4 + 255) >> 8;
    if (b > 2048) b = 2048;
    cvt_f32_bf16<<<dim3((unsigned)b), dim3(256), 0, stream>>>(
        (const float4*)src, (ushort4v*)dst, n4);
  };
  cvt(x,   xb,    (size_t)M * D);
  cvt(gW1, w1cat, (size_t)H * D);
  cvt(eW1, w1cat + (size_t)H * D, (size_t)E * H * D);
  cvt(gW2, gW2b,  (size_t)H * H);
  cvt(gW3, gW3b,  (size_t)E * H);
  cvt(eW2, eW2b,  (size_t)E * D * H);
  hipMemcpyAsync(b1cat, gb1, (size_t)H * 4, hipMemcpyDeviceToDevice, stream);
  hipMemcpyAsync(b1cat + H, eb1, (size_t)E * H * 4, hipMemcpyDeviceToDevice, stream);

  // fused layer-1: h_cat[seg s] = gelu(x @ [gW1;eW1]^T + b1cat)  [M, 36864]
  gemm128_k<0><<<dim3(NCAT / 128, M / 128), dim3(256), 0, stream>>>(
      xb, D, w1cat, b1cat, h_cat, SEG, NCAT, D);

  // gate2 and unweighted expert2 concurrently (one 3072-block launch);
  // eo_bf overwrites w1cat (safe: layer-1 already consumed it)
  merged_g2e2<<<dim3(3072), dim3(256), 0, stream>>>(
      h_cat, SEG, gW2b, gb2, g2b, eW2b, eb2, eo_bf, (size_t)M * D, D, H);
  // softmax weights
  gate_softmax<<<dim3(M), dim3(256), 0, stream>>>(g2b, gW3b, gb3, wP, H);
  // out = sum_e w[:,e] * eo[e]
  reduce8w<<<dim3(2048), dim3(256), 0, stream>>>(
      eo_bf, wP, outP, (int)((size_t)M * D / 8), 7 /* log2(D/8) */);
}